// Round 1
// baseline (1071.522 us; speedup 1.0000x reference)
//
#include <hip/hip_runtime.h>
#include <math.h>

#define WAVE 64
#define SCAN_BS 1024

// ---------------- CSR build ----------------

__global__ void deg_count_k(const int* __restrict__ ei, int* __restrict__ deg, int E) {
    int e = blockIdx.x * blockDim.x + threadIdx.x;
    if (e < E) atomicAdd(&deg[ei[E + e]], 1);   // dst row is ei[E..2E)
}

__global__ void dinv_k(const int* __restrict__ deg, float* __restrict__ dinv, int N) {
    int i = blockIdx.x * blockDim.x + threadIdx.x;
    if (i < N) dinv[i] = rsqrtf((float)(deg[i] + 1));  // +1 for self-loop
}

__global__ void scan_blocks_k(const int* __restrict__ deg, int* __restrict__ rowstart,
                              int* __restrict__ bsums, int N) {
    __shared__ int sm[SCAN_BS];
    int t = threadIdx.x;
    int i = blockIdx.x * SCAN_BS + t;
    int v = (i < N) ? deg[i] : 0;
    sm[t] = v;
    __syncthreads();
    for (int off = 1; off < SCAN_BS; off <<= 1) {
        int x = (t >= off) ? sm[t - off] : 0;
        __syncthreads();
        sm[t] += x;
        __syncthreads();
    }
    if (i < N) rowstart[i] = sm[t] - v;          // block-local exclusive
    if (t == SCAN_BS - 1) bsums[blockIdx.x] = sm[t];
}

__global__ void scan_sums_k(const int* __restrict__ bsums, int* __restrict__ boffs,
                            int* __restrict__ rowstart, int NB, int N) {
    __shared__ int sm[SCAN_BS];
    int t = threadIdx.x;
    int v = (t < NB) ? bsums[t] : 0;
    sm[t] = v;
    __syncthreads();
    for (int off = 1; off < SCAN_BS; off <<= 1) {
        int x = (t >= off) ? sm[t - off] : 0;
        __syncthreads();
        sm[t] += x;
        __syncthreads();
    }
    if (t < NB) boffs[t] = sm[t] - v;
    if (t == SCAN_BS - 1) rowstart[N] = sm[t];   // total = E
}

__global__ void scan_add_k(int* __restrict__ rowstart, const int* __restrict__ boffs, int N) {
    int i = blockIdx.x * SCAN_BS + threadIdx.x;
    if (i < N) rowstart[i] += boffs[blockIdx.x];
}

__global__ void fill_k(const int* __restrict__ ei, const int* __restrict__ rowstart,
                       int* __restrict__ fill, int* __restrict__ csr, int E) {
    int e = blockIdx.x * blockDim.x + threadIdx.x;
    if (e < E) {
        int d = ei[E + e];
        int p = rowstart[d] + atomicAdd(&fill[d], 1);
        csr[p] = ei[e];                           // src row is ei[0..E)
    }
}

// ---------------- Aggregation: out[i] = dinv[i]*(sum_{e:dst=i} dinv[src]*in[src] + dinv[i]*in[i]) ----------------
// G lanes per node (lane -> channel), 64/G nodes per wave. C = active channels (C <= G).

template <int G, int C>
__global__ __launch_bounds__(256) void agg_k(
    const float* __restrict__ in, float* __restrict__ out,
    const int* __restrict__ rowstart, const int* __restrict__ csr,
    const float* __restrict__ dinv, const float* __restrict__ bias,
    int N, int relu) {
    const int NPW = WAVE / G;
    int tid  = blockIdx.x * blockDim.x + threadIdx.x;
    int lane = threadIdx.x & (WAVE - 1);
    int wave = tid >> 6;
    int node = wave * NPW + (lane / G);
    int c    = lane % G;
    if (node >= N) return;                         // whole G-group exits together
    int s = rowstart[node];
    int e = rowstart[node + 1];
    float acc = 0.f;
    int j = s;
    // main: batches of G edges; lane c preloads edge j+c, then broadcast via shfl
    for (; j + G <= e; j += G) {
        int   es = csr[j + c];
        float ef = dinv[es];
#pragma unroll
        for (int k = 0; k < G; ++k) {
            int   sk = __shfl(es, k, G);
            float fk = __shfl(ef, k, G);
            if (c < C) acc += fk * in[(long)sk * C + c];
        }
    }
    if (j < e) {
        int cnt = e - j;
        int   es = 0;
        float ef = 0.f;
        if (j + c < e) { es = csr[j + c]; ef = dinv[es]; }
        for (int k = 0; k < cnt; ++k) {
            int   sk = __shfl(es, k, G);
            float fk = __shfl(ef, k, G);
            if (c < C) acc += fk * in[(long)sk * C + c];
        }
    }
    if (c < C) {
        float di = dinv[node];
        acc += di * in[(long)node * C + c];        // self-loop
        acc *= di;
        if (bias) acc += bias[c];
        if (relu) acc = fmaxf(acc, 0.f);
        out[(long)node * C + c] = acc;
    }
}

// ---------------- Tiny GEMM: out = act(in[N,Ci] @ W[Ci,Co] (+bias)) ----------------

template <int Ci, int Co>
__global__ __launch_bounds__(256) void gemm_k(
    const float* __restrict__ in, const float* __restrict__ W,
    const float* __restrict__ bias, float* __restrict__ out,
    int N, int relu) {
    __shared__ float sW[Ci * Co];
    __shared__ float sB[Co];
    int t = threadIdx.x;
    for (int i = t; i < Ci * Co; i += blockDim.x) sW[i] = W[i];
    for (int i = t; i < Co; i += blockDim.x) sB[i] = bias ? bias[i] : 0.f;
    __syncthreads();
    int node = blockIdx.x * blockDim.x + t;
    if (node >= N) return;
    const float* row = in + (long)node * Ci;
    float r[Ci];
#pragma unroll
    for (int i = 0; i < Ci; ++i) r[i] = row[i];
    float acc[Co];
#pragma unroll
    for (int o = 0; o < Co; ++o) acc[o] = sB[o];
#pragma unroll
    for (int i = 0; i < Ci; ++i) {
        float ri = r[i];
#pragma unroll
        for (int o = 0; o < Co; ++o) acc[o] += ri * sW[i * Co + o];
    }
#pragma unroll
    for (int o = 0; o < Co; ++o) {
        float a = acc[o];
        if (relu) a = fmaxf(a, 0.f);
        out[(long)node * Co + o] = a;
    }
}

// ---------------- Pooling + log_softmax ----------------

__global__ void pool_init_k(float* pooled, int n) {
    int i = blockIdx.x * blockDim.x + threadIdx.x;
    if (i < n) pooled[i] = -INFINITY;
}

__device__ inline void atomicMaxF(float* addr, float v) {
    if (v >= 0.f) atomicMax((int*)addr, __float_as_int(v));
    else          atomicMin((unsigned int*)addr, __float_as_uint(v));
}

__global__ void pool_max_k(const float* __restrict__ nodeout, const int* __restrict__ batch,
                           float* __restrict__ pooled, int N) {
    int i = blockIdx.x * blockDim.x + threadIdx.x;
    if (i < N) {
        int g = batch[i];
        atomicMaxF(&pooled[g * 2 + 0], nodeout[i * 2 + 0]);
        atomicMaxF(&pooled[g * 2 + 1], nodeout[i * 2 + 1]);
    }
}

__global__ void finalize_k(const float* __restrict__ pooled, float* __restrict__ out, int Gn) {
    int g = blockIdx.x * blockDim.x + threadIdx.x;
    if (g < Gn) {
        float a = pooled[g * 2 + 0], b = pooled[g * 2 + 1];
        if (!isfinite(a)) a = 0.f;
        if (!isfinite(b)) b = 0.f;
        float m = fmaxf(a, b);
        float lse = m + logf(expf(a - m) + expf(b - m));
        out[g * 2 + 0] = a - lse;
        out[g * 2 + 1] = b - lse;
    }
}

// ---------------- launch ----------------

extern "C" void kernel_launch(void* const* d_in, const int* in_sizes, int n_in,
                              void* d_out, int out_size, void* d_ws, size_t ws_size,
                              hipStream_t stream) {
    const float* x     = (const float*)d_in[0];
    const int*   ei    = (const int*)d_in[1];
    const int*   batch = (const int*)d_in[2];
    const float* W1 = (const float*)d_in[3];
    const float* b1 = (const float*)d_in[4];
    const float* W2 = (const float*)d_in[5];
    const float* b2 = (const float*)d_in[6];
    const float* W3 = (const float*)d_in[7];
    const float* b3 = (const float*)d_in[8];
    const float* W4 = (const float*)d_in[9];
    const float* b4 = (const float*)d_in[10];
    float* out = (float*)d_out;

    int N  = in_sizes[0] / 14;
    int E  = in_sizes[1] / 2;
    int Gn = out_size / 2;

    char* ws = (char*)d_ws;
    size_t off = 0;
    auto alloc = [&](size_t bytes) -> char* {
        char* p = ws + off;
        off = (off + bytes + 255) & ~(size_t)255;
        return p;
    };
    int*   deg      = (int*)alloc((size_t)N * 4);
    int*   fill     = (int*)alloc((size_t)N * 4);
    int*   rowstart = (int*)alloc((size_t)(N + 1) * 4);
    int*   bsums    = (int*)alloc(4096);
    int*   boffs    = (int*)alloc(4096);
    float* dinv     = (float*)alloc((size_t)N * 4);
    int*   csr      = (int*)alloc((size_t)E * 4);
    float* p0       = (float*)alloc((size_t)N * 14 * 4);  // later reused as node_out [N,2]
    float* bufA     = (float*)alloc((size_t)N * 64 * 4);
    float* bufB     = (float*)alloc((size_t)N * 64 * 4);
    float* pooled   = (float*)alloc((size_t)Gn * 2 * 4);
    (void)ws_size; (void)n_in;

    int NB = (N + SCAN_BS - 1) / SCAN_BS;

    hipMemsetAsync(deg, 0, (size_t)N * 4, stream);
    hipMemsetAsync(fill, 0, (size_t)N * 4, stream);
    deg_count_k<<<(E + 255) / 256, 256, 0, stream>>>(ei, deg, E);
    dinv_k<<<(N + 255) / 256, 256, 0, stream>>>(deg, dinv, N);
    scan_blocks_k<<<NB, SCAN_BS, 0, stream>>>(deg, rowstart, bsums, N);
    scan_sums_k<<<1, SCAN_BS, 0, stream>>>(bsums, boffs, rowstart, NB, N);
    scan_add_k<<<NB, SCAN_BS, 0, stream>>>(rowstart, boffs, N);
    fill_k<<<(E + 255) / 256, 256, 0, stream>>>(ei, rowstart, fill, csr, E);

    // layer 1: h1 = relu((A x) @ W1 + b1); propagate at 14 dims
    {
        int waves  = (N + 3) / 4;                          // 4 nodes/wave (G=16)
        int blocks = (waves * 64 + 255) / 256;
        agg_k<16, 14><<<blocks, 256, 0, stream>>>(x, p0, rowstart, csr, dinv, nullptr, N, 0);
    }
    gemm_k<14, 64><<<(N + 255) / 256, 256, 0, stream>>>(p0, W1, b1, bufA, N, 1);

    // layer 2: h2 = relu((A h1) @ W2 + b2)
    {
        int blocks = (N * 64 + 255) / 256;                 // 1 node/wave (G=64)
        agg_k<64, 64><<<blocks, 256, 0, stream>>>(bufA, bufB, rowstart, csr, dinv, nullptr, N, 0);
    }
    gemm_k<64, 64><<<(N + 255) / 256, 256, 0, stream>>>(bufB, W2, b2, bufA, N, 1);

    // layer 3: h3 = relu(A (h2 @ W3) + b3); GEMM first (32 < 64)
    gemm_k<64, 32><<<(N + 255) / 256, 256, 0, stream>>>(bufA, W3, nullptr, bufB, N, 0);
    {
        int waves  = (N + 1) / 2;                          // 2 nodes/wave (G=32)
        int blocks = (waves * 64 + 255) / 256;
        agg_k<32, 32><<<blocks, 256, 0, stream>>>(bufB, bufA, rowstart, csr, dinv, b3, N, 1);
    }

    // layer 4: out = A (h3 @ W4) + b4
    gemm_k<32, 2><<<(N + 255) / 256, 256, 0, stream>>>(bufA, W4, nullptr, bufB, N, 0);
    {
        int waves  = (N + 31) / 32;                        // 32 nodes/wave (G=2)
        int blocks = (waves * 64 + 255) / 256;
        agg_k<2, 2><<<blocks, 256, 0, stream>>>(bufB, p0, rowstart, csr, dinv, b4, N, 0);
    }

    pool_init_k<<<(Gn * 2 + 255) / 256, 256, 0, stream>>>(pooled, Gn * 2);
    pool_max_k<<<(N + 255) / 256, 256, 0, stream>>>(p0, batch, pooled, N);
    finalize_k<<<(Gn + 255) / 256, 256, 0, stream>>>(pooled, out, Gn);
}